// Round 2
// baseline (1036.901 us; speedup 1.0000x reference)
//
#include <hip/hip_runtime.h>

#define N_ROWS 65536          // 16*4096
#define DIM    256
#define KCB    1024

// d_out layout (floats), in reference return order
#define Q_OFF    0
#define ENC_OFF  (N_ROWS * DIM)                  // 16777216
#define IDX_OFF  (ENC_OFF + N_ROWS * KCB)        // 83886080
#define LOSS_OFF (IDX_OFF + N_ROWS)              // 83951616

// scratch carved out of the encodings region (overwritten by final kernel)
#define ET_OFF   (ENC_OFF + 0)                   // 1024*256 floats = E^T
#define NRM_OFF  (ENC_OFF + 262144)              // 1024 floats ||e_k||^2
#define IDXI_OFF (ENC_OFF + 263168)              // 65536 ints (argmin result)
#define PART_OFF (ENC_OFF + 328704)              // 16384 floats loss partials

// ---------------------------------------------------------------------------
// prep: E^T for coalesced gather + per-code squared norms
__global__ __launch_bounds__(64)
void vq_prep(const float* __restrict__ E, float* __restrict__ out) {
    float* ET  = out + ET_OFF;
    float* nrm = out + NRM_OFF;
    const int k = blockIdx.x;     // 0..1023
    const int t = threadIdx.x;    // 0..63
    float v[4];
    float s = 0.f;
#pragma unroll
    for (int i = 0; i < 4; ++i) {
        float e = E[(size_t)(t * 4 + i) * KCB + k];
        v[i] = e;
        s += e * e;
    }
    *(float4*)(ET + (size_t)k * DIM + t * 4) = *(float4*)v;
#pragma unroll
    for (int off = 32; off >= 1; off >>= 1) s += __shfl_xor(s, off);
    if (t == 0) nrm[k] = s;
}

// ---------------------------------------------------------------------------
// argmin over codebook: tiled f32 GEMM (64 rows/block x 256-col tiles, BK=32)
// thread micro-tile: 4 rows x 16 cols (cols interleaved cg*4 + j4*64)
__global__ __launch_bounds__(256, 3)
void vq_argmin(const float* __restrict__ X, const float* __restrict__ E,
               float* __restrict__ out) {
    __shared__ __align__(16) float XsT[32][68];   // [d][row], padded
    __shared__ __align__(16) float Es[32][256];   // [d][col]
    const float* nrm = out + NRM_OFF;
    const int tid  = threadIdx.x;
    const int row0 = blockIdx.x * 64;
    const int rg   = tid >> 4;   // 0..15 -> rows rg*4..rg*4+3
    const int cg   = tid & 15;   // col group

    float minv[4];
    int   mini[4];
#pragma unroll
    for (int i = 0; i < 4; ++i) { minv[i] = 3.4e38f; mini[i] = 0; }

    for (int ct = 0; ct < 4; ++ct) {
        const int col0 = ct * 256;
        float acc[4][16];
#pragma unroll
        for (int i = 0; i < 4; ++i)
#pragma unroll
            for (int j = 0; j < 16; ++j) acc[i][j] = 0.f;

        for (int kk = 0; kk < 8; ++kk) {
            const int d0 = kk * 32;
            __syncthreads();   // protect LDS from previous iter readers
            // stage X tile (64 rows x 32 d), transposed into XsT[d][r]
#pragma unroll
            for (int p = 0; p < 2; ++p) {
                int g = p * 256 + tid;
                int r = g >> 3, d4 = g & 7;
                float4 v = *(const float4*)(X + (size_t)(row0 + r) * DIM + d0 + d4 * 4);
                XsT[d4 * 4 + 0][r] = v.x;
                XsT[d4 * 4 + 1][r] = v.y;
                XsT[d4 * 4 + 2][r] = v.z;
                XsT[d4 * 4 + 3][r] = v.w;
            }
            // stage E tile (32 d x 256 cols)
#pragma unroll
            for (int p = 0; p < 8; ++p) {
                int g = p * 256 + tid;
                int d = g >> 6, c4 = g & 63;
                *(float4*)&Es[d][c4 * 4] =
                    *(const float4*)(E + (size_t)(d0 + d) * KCB + col0 + c4 * 4);
            }
            __syncthreads();
#pragma unroll 4
            for (int d = 0; d < 32; ++d) {
                float xr[4];
                *(float4*)xr = *(const float4*)&XsT[d][rg * 4];
                float ev[16];
                *(float4*)&ev[0]  = *(const float4*)&Es[d][cg * 4];
                *(float4*)&ev[4]  = *(const float4*)&Es[d][cg * 4 + 64];
                *(float4*)&ev[8]  = *(const float4*)&Es[d][cg * 4 + 128];
                *(float4*)&ev[12] = *(const float4*)&Es[d][cg * 4 + 192];
#pragma unroll
                for (int i = 0; i < 4; ++i)
#pragma unroll
                    for (int j = 0; j < 16; ++j)
                        acc[i][j] = fmaf(xr[i], ev[j], acc[i][j]);
            }
        }
        // distances for this col tile + running argmin (ascending col order)
#pragma unroll
        for (int j = 0; j < 16; ++j) {
            const int col = col0 + cg * 4 + ((j >> 2) << 6) + (j & 3);
            const float nv = nrm[col];
#pragma unroll
            for (int i = 0; i < 4; ++i) {
                float dist = fmaf(-2.f, acc[i][j], nv);
                if (dist < minv[i]) { minv[i] = dist; mini[i] = col; }
            }
        }
    }
    // reduce across the 16 lanes sharing this row group (first-index tie-break)
#pragma unroll
    for (int off = 1; off < 16; off <<= 1) {
#pragma unroll
        for (int i = 0; i < 4; ++i) {
            float ov = __shfl_xor(minv[i], off);
            int   oi = __shfl_xor(mini[i], off);
            if (ov < minv[i] || (ov == minv[i] && oi < mini[i])) {
                minv[i] = ov; mini[i] = oi;
            }
        }
    }
    if (cg == 0) {
        int* idxp = (int*)(out + IDXI_OFF);
#pragma unroll
        for (int i = 0; i < 4; ++i) idxp[row0 + rg * 4 + i] = mini[i];
    }
}

// ---------------------------------------------------------------------------
// outputs: quantized_st (gather from E^T), indices-as-float, loss partials
__global__ __launch_bounds__(256)
void vq_outputs(const float* __restrict__ X, float* __restrict__ out) {
    const float* ET  = out + ET_OFF;
    const int*   idx = (const int*)(out + IDXI_OFF);
    float*       part = out + PART_OFF;
    __shared__ float red[4];
    const int row  = blockIdx.x * 4 + (threadIdx.x >> 6);
    const int lane = threadIdx.x & 63;
    const int id   = idx[row];
    float4 e = *(const float4*)(ET + (size_t)id * DIM + lane * 4);
    float4 x = *(const float4*)(X + (size_t)row * DIM + lane * 4);
    float dx = e.x - x.x, dy = e.y - x.y, dz = e.z - x.z, dw = e.w - x.w;
    float4 q;  // straight-through: x + (q - x), matching reference fp ops
    q.x = x.x + dx; q.y = x.y + dy; q.z = x.z + dz; q.w = x.w + dw;
    *(float4*)(out + Q_OFF + (size_t)row * DIM + lane * 4) = q;
    float s = dx * dx + dy * dy + dz * dz + dw * dw;
#pragma unroll
    for (int off = 32; off >= 1; off >>= 1) s += __shfl_xor(s, off);
    if (lane == 0) {
        red[threadIdx.x >> 6] = s;
        out[IDX_OFF + row] = (float)id;
    }
    __syncthreads();
    if (threadIdx.x == 0) part[blockIdx.x] = red[0] + red[1] + red[2] + red[3];
}

// ---------------------------------------------------------------------------
// finalize loss = 1.25 * mean((q-x)^2)   (f64 accumulation of block partials)
__global__ __launch_bounds__(256)
void vq_loss(float* __restrict__ out) {
    const float* part = out + PART_OFF;
    __shared__ double red[256];
    const int tid = threadIdx.x;
    double s = 0.0;
    for (int i = tid; i < 16384; i += 256) s += (double)part[i];
    red[tid] = s;
    __syncthreads();
    for (int off = 128; off > 0; off >>= 1) {
        if (tid < off) red[tid] += red[tid + off];
        __syncthreads();
    }
    if (tid == 0)
        out[LOSS_OFF] = (float)(1.25 * red[0] / (double)((size_t)N_ROWS * DIM));
}

// ---------------------------------------------------------------------------
// encodings: zero the whole one-hot region and set ones (reads float indices)
__global__ __launch_bounds__(256)
void vq_encodings(float* __restrict__ out) {
    const float* idxf = out + IDX_OFF;
    float4* enc4 = (float4*)(out + ENC_OFF);
    const size_t total4 = (size_t)N_ROWS * KCB / 4;  // 16777216
    const size_t stride = (size_t)gridDim.x * blockDim.x;
    for (size_t g = (size_t)blockIdx.x * blockDim.x + threadIdx.x; g < total4; g += stride) {
        int n  = (int)(g >> 8);
        int c0 = ((int)g & 255) * 4;
        int r  = (int)idxf[n] - c0;
        float4 v;
        v.x = (r == 0) ? 1.f : 0.f;
        v.y = (r == 1) ? 1.f : 0.f;
        v.z = (r == 2) ? 1.f : 0.f;
        v.w = (r == 3) ? 1.f : 0.f;
        enc4[g] = v;
    }
}

// ---------------------------------------------------------------------------
extern "C" void kernel_launch(void* const* d_in, const int* in_sizes, int n_in,
                              void* d_out, int out_size, void* d_ws, size_t ws_size,
                              hipStream_t stream) {
    const float* X = (const float*)d_in[0];   // inputs [16,4096,256]
    const float* E = (const float*)d_in[1];   // embeddings [256,1024]
    float* out = (float*)d_out;

    vq_prep     <<<1024,  64, 0, stream>>>(E, out);
    vq_argmin   <<<1024, 256, 0, stream>>>(X, E, out);
    vq_outputs  <<<16384, 256, 0, stream>>>(X, out);
    vq_loss     <<<1,    256, 0, stream>>>(out);
    vq_encodings<<<2048, 256, 0, stream>>>(out);
}

// Round 5
// 853.177 us; speedup vs baseline: 1.2153x; 1.2153x over previous
//
#include <hip/hip_runtime.h>

#define N_ROWS 65536          // 16*4096
#define DIM    256
#define KCB    1024

// d_out layout (floats), in reference return order
#define Q_OFF    0
#define ENC_OFF  (N_ROWS * DIM)                  // 16777216
#define IDX_OFF  (ENC_OFF + N_ROWS * KCB)        // 83886080
#define LOSS_OFF (IDX_OFF + N_ROWS)              // 83951616

// scratch carved out of the encodings region (overwritten by final kernel)
#define ET_OFF   (ENC_OFF + 0)                   // 262144 f32: E^T
#define NRM_OFF  (ENC_OFF + 262144)              // 1024 f32: ||e||^2
#define IDXI_OFF (ENC_OFF + 263168)              // 65536 int: final argmin
#define PART_OFF (ENC_OFF + 328704)              // 16384 f32: loss partials
#define AMB_OFF  (ENC_OFF + 345088)              // int counter + 65536 int list
#define PMIN_OFF (ENC_OFF + 524288)              // 65536*16 float4 partial minima
#define A2_OFF   (ENC_OFF + 4718592)             // bf16 [65536][512] {hi|lo}
#define BST_OFF  (ENC_OFF + 21495808)            // bf16 [1024][512] {ehi|elo}

#define TAU 0.5f   // ambiguity gap; worst-case split-bf16 dist error ~0.015

typedef short  bf16x8 __attribute__((ext_vector_type(8)));
typedef float  f32x4  __attribute__((ext_vector_type(4)));
typedef unsigned short u16x8 __attribute__((ext_vector_type(8)));
#define AS1 __attribute__((address_space(1)))
#define AS3 __attribute__((address_space(3)))

__device__ inline unsigned short f2bf(float x) {
    unsigned u = __float_as_uint(x);
    return (unsigned short)((u + 0x7FFFu + ((u >> 16) & 1u)) >> 16);
}
__device__ inline float bf2f(unsigned short b) {
    return __uint_as_float(((unsigned)b) << 16);
}

// ---------------------------------------------------------------------------
// split X (f32) -> A2 [row][512] bf16: [0,256)=hi, [256,512)=lo
__global__ __launch_bounds__(256)
void vq_prep_a(const float* __restrict__ X, float* __restrict__ out) {
    unsigned short* A2 = (unsigned short*)(out + A2_OFF);
    int gid = blockIdx.x * 256 + threadIdx.x;   // 2M threads, 8 floats each
    int row = gid >> 5;
    int d0  = (gid & 31) * 8;
    const float* xp = X + (size_t)row * DIM + d0;
    float4 v0 = *(const float4*)xp;
    float4 v1 = *(const float4*)(xp + 4);
    float xv[8] = {v0.x, v0.y, v0.z, v0.w, v1.x, v1.y, v1.z, v1.w};
    u16x8 h, l;
#pragma unroll
    for (int i = 0; i < 8; ++i) {
        unsigned short hb = f2bf(xv[i]);
        h[i] = hb;
        l[i] = f2bf(xv[i] - bf2f(hb));
    }
    *(u16x8*)(A2 + (size_t)row * 512 + d0) = h;
    *(u16x8*)(A2 + (size_t)row * 512 + 256 + d0) = l;
}

// ---------------------------------------------------------------------------
// E [256][1024] -> ET [1024][256] f32, nrm [1024], B2 [1024][512] bf16 {hi|lo}
// NOTE: the s += e*e chain + butterfly order must stay identical to the
// known-good round-2 prep (rescore replicates its consumers bit-exactly).
__global__ __launch_bounds__(64)
void vq_prep_b(const float* __restrict__ E, float* __restrict__ out) {
    float* ET  = out + ET_OFF;
    float* nrm = out + NRM_OFF;
    unsigned short* B2 = (unsigned short*)(out + BST_OFF);
    const int k = blockIdx.x, t = threadIdx.x;
    float v[4]; float s = 0.f;
    ushort4 hb, lb;
#pragma unroll
    for (int i = 0; i < 4; ++i) {
        float e = E[(size_t)(t * 4 + i) * KCB + k];
        v[i] = e; s += e * e;
        unsigned short h = f2bf(e);
        ((unsigned short*)&hb)[i] = h;
        ((unsigned short*)&lb)[i] = f2bf(e - bf2f(h));
    }
    *(float4*)(ET + (size_t)k * DIM + t * 4) = *(float4*)v;
    *(ushort4*)(B2 + (size_t)k * 512 + t * 4) = hb;
    *(ushort4*)(B2 + (size_t)k * 512 + 256 + t * 4) = lb;
#pragma unroll
    for (int off = 32; off >= 1; off >>= 1) s += __shfl_xor(s, off);
    if (t == 0) nrm[k] = s;
    if (k == 0 && t == 0) ((int*)(out + AMB_OFF))[0] = 0;   // ambiguous counter
}

// ---------------------------------------------------------------------------
// MFMA distance GEMM: sim = x_hi.e_hi + x_hi.e_lo + x_lo.e_hi  (K=768 virtual)
// 128x128 tile, BK=64, 4 waves, 16x16x32 bf16 MFMA, global_load_lds width 16.
// Epilogue: per-row top-2 -> pmin[row][cb*2 + wc]  (16 slots per row).
__global__ __launch_bounds__(256, 2)
void vq_gemm(float* __restrict__ out) {
    __shared__ short lds[16384];   // A tile [128][64] @0, B tile [128][64] @8192
    const unsigned short* A2 = (const unsigned short*)(out + A2_OFF);
    const unsigned short* B2 = (const unsigned short*)(out + BST_OFF);
    const float* nrm = out + NRM_OFF;
    float4* pmin = (float4*)(out + PMIN_OFF);

    const int orig = blockIdx.x;
    const int mapped = (orig & 7) * 512 + (orig >> 3);   // XCD-contiguous
    const int rb = mapped >> 3, cb = mapped & 7;
    const int row0 = rb * 128, col0 = cb * 128;

    const int tid = threadIdx.x;
    const int lane = tid & 63, l15 = lane & 15, lhi = lane >> 4;
    const int w = tid >> 6, wr = w >> 1, wc = w & 1;

    f32x4 acc[4][4];
#pragma unroll
    for (int i = 0; i < 4; ++i)
#pragma unroll
        for (int j = 0; j < 4; ++j) acc[i][j] = (f32x4){0.f, 0.f, 0.f, 0.f};

    const int sr = tid >> 3;          // staging row within 32-row chunk group
    const int sk = (tid & 7) * 8;     // staging k offset (bf16 units)
    const int wofs = (tid & 192) * 16;  // wave-uniform LDS byte base piece

    for (int ks = 0; ks < 12; ++ks) {
        const int phase = ks >> 2, kr = (ks & 3) * 64;
        const int ak = (phase == 2 ? 256 : 0) + kr;   // hi,hi,lo
        const int bk = (phase == 1 ? 256 : 0) + kr;   // ehi,elo,ehi
        __syncthreads();
#pragma unroll
        for (int i = 0; i < 4; ++i) {
            int r = i * 32 + sr;
            __builtin_amdgcn_global_load_lds(
                (const AS1 unsigned*)(A2 + (size_t)(row0 + r) * 512 + ak + sk),
                (AS3 unsigned*)((char*)lds + i * 4096 + wofs), 16, 0, 0);
        }
#pragma unroll
        for (int i = 0; i < 4; ++i) {
            int r = i * 32 + sr;
            __builtin_amdgcn_global_load_lds(
                (const AS1 unsigned*)(B2 + (size_t)(col0 + r) * 512 + bk + sk),
                (AS3 unsigned*)((char*)lds + 16384 + i * 4096 + wofs), 16, 0, 0);
        }
        asm volatile("s_waitcnt vmcnt(0)" ::: "memory");
        __syncthreads();
#pragma unroll
        for (int kk = 0; kk < 2; ++kk) {
            bf16x8 af[4], bfr[4];
#pragma unroll
            for (int mi = 0; mi < 4; ++mi)
                af[mi] = *(const bf16x8*)&lds[(wr * 64 + mi * 16 + l15) * 64 + kk * 32 + lhi * 8];
#pragma unroll
            for (int ni = 0; ni < 4; ++ni)
                bfr[ni] = *(const bf16x8*)&lds[8192 + (wc * 64 + ni * 16 + l15) * 64 + kk * 32 + lhi * 8];
#pragma unroll
            for (int mi = 0; mi < 4; ++mi)
#pragma unroll
                for (int ni = 0; ni < 4; ++ni)
                    acc[mi][ni] = __builtin_amdgcn_mfma_f32_16x16x32_bf16(
                        af[mi], bfr[ni], acc[mi][ni], 0, 0, 0);
        }
    }

    // epilogue: dist = nrm - 2*sim; per-row top-2 over this wave's 64 cols
    float nv[4];
#pragma unroll
    for (int ni = 0; ni < 4; ++ni) nv[ni] = nrm[col0 + wc * 64 + ni * 16 + l15];
#pragma unroll
    for (int mi = 0; mi < 4; ++mi)
#pragma unroll
        for (int j = 0; j < 4; ++j) {
            float a = 3.4e38f, b = 3.4e38f; int ia = 0;
#pragma unroll
            for (int ni = 0; ni < 4; ++ni) {
                float dist = fmaf(-2.f, acc[mi][ni][j], nv[ni]);
                int col = col0 + wc * 64 + ni * 16 + l15;
                if (dist < a) { b = a; a = dist; ia = col; }
                else if (dist < b) b = dist;
            }
#pragma unroll
            for (int off = 1; off < 16; off <<= 1) {
                float oa = __shfl_xor(a, off);
                float ob = __shfl_xor(b, off);
                int   oi = __shfl_xor(ia, off);
                if (oa < a || (oa == a && oi < ia)) { b = fminf(a, ob); a = oa; ia = oi; }
                else b = fminf(b, oa);
            }
            if (l15 == 0) {
                int grow = row0 + wr * 64 + mi * 16 + lhi * 4 + j;
                float4 pv;
                pv.x = a; pv.y = b; pv.z = __int_as_float(ia); pv.w = 0.f;
                pmin[(size_t)grow * 16 + cb * 2 + wc] = pv;   // per-(cb,wc) slot
            }
        }
}

// ---------------------------------------------------------------------------
// merge 16 partials per row; flag ambiguous rows (gap < TAU)
__global__ __launch_bounds__(256)
void vq_combine(float* __restrict__ out) {
    const float4* pmin = (const float4*)(out + PMIN_OFF);
    int* idxi = (int*)(out + IDXI_OFF);
    int* amb  = (int*)(out + AMB_OFF);
    const int row = blockIdx.x * 256 + threadIdx.x;
    float a = 3.4e38f, b = 3.4e38f; int ia = 0;
#pragma unroll
    for (int s = 0; s < 16; ++s) {
        float4 p = pmin[(size_t)row * 16 + s];
        int oi = __float_as_int(p.z);
        if (p.x < a || (p.x == a && oi < ia)) { b = fminf(a, p.y); a = p.x; ia = oi; }
        else b = fminf(b, p.x);
    }
    idxi[row] = ia;
    if (b - a < TAU) {
        int pos = atomicAdd(amb, 1);
        if (pos < 65536) amb[1 + pos] = row;
    }
}

// ---------------------------------------------------------------------------
// rescore of ambiguous rows: BIT-EXACT replica of the known-good round-2 f32
// arithmetic (fmaf chain d=0..255, dist = fmaf(-2, acc, nrm), first-index
// argmin). Must NOT be "more exact" — near-ties must resolve like numpy/f32.
__global__ __launch_bounds__(256)
void vq_rescore(const float* __restrict__ X, const float* __restrict__ E,
                float* __restrict__ out) {
    __shared__ float xs[256];
    __shared__ float rv[256];
    __shared__ int   ri[256];
    const float* nrm = out + NRM_OFF;
    const int* amb = (const int*)(out + AMB_OFF);
    int* idxi = (int*)(out + IDXI_OFF);
    int count = amb[0]; if (count > 65536) count = 65536;
    for (int it = blockIdx.x; it < count; it += gridDim.x) {
        const int row = amb[1 + it];
        __syncthreads();
        xs[threadIdx.x] = X[(size_t)row * DIM + threadIdx.x];
        __syncthreads();
        float best = 3.4e38f; int bi = 0;
        for (int cc = 0; cc < 4; ++cc) {
            const int code = cc * 256 + threadIdx.x;   // ascending per thread
            float acc = 0.f;
            for (int d = 0; d < 256; ++d)
                acc = fmaf(xs[d], E[(size_t)d * KCB + code], acc);
            float dist = fmaf(-2.f, acc, nrm[code]);
            if (dist < best) { best = dist; bi = code; }
        }
        rv[threadIdx.x] = best; ri[threadIdx.x] = bi;
        __syncthreads();
        for (int off = 128; off > 0; off >>= 1) {
            if (threadIdx.x < off) {
                float ov = rv[threadIdx.x + off]; int oi = ri[threadIdx.x + off];
                if (ov < rv[threadIdx.x] || (ov == rv[threadIdx.x] && oi < ri[threadIdx.x])) {
                    rv[threadIdx.x] = ov; ri[threadIdx.x] = oi;
                }
            }
            __syncthreads();
        }
        if (threadIdx.x == 0) idxi[row] = ri[0];
    }
}

// ---------------------------------------------------------------------------
// outputs: quantized_st (gather from E^T), indices-as-float, loss partials
__global__ __launch_bounds__(256)
void vq_outputs(const float* __restrict__ X, float* __restrict__ out) {
    const float* ET  = out + ET_OFF;
    const int*   idx = (const int*)(out + IDXI_OFF);
    float*       part = out + PART_OFF;
    __shared__ float red[4];
    const int row  = blockIdx.x * 4 + (threadIdx.x >> 6);
    const int lane = threadIdx.x & 63;
    const int id   = idx[row];
    float4 e = *(const float4*)(ET + (size_t)id * DIM + lane * 4);
    float4 x = *(const float4*)(X + (size_t)row * DIM + lane * 4);
    float dx = e.x - x.x, dy = e.y - x.y, dz = e.z - x.z, dw = e.w - x.w;
    float4 q;
    q.x = x.x + dx; q.y = x.y + dy; q.z = x.z + dz; q.w = x.w + dw;
    *(float4*)(out + Q_OFF + (size_t)row * DIM + lane * 4) = q;
    float s = dx * dx + dy * dy + dz * dz + dw * dw;
#pragma unroll
    for (int off = 32; off >= 1; off >>= 1) s += __shfl_xor(s, off);
    if (lane == 0) {
        red[threadIdx.x >> 6] = s;
        out[IDX_OFF + row] = (float)id;
    }
    __syncthreads();
    if (threadIdx.x == 0) part[blockIdx.x] = red[0] + red[1] + red[2] + red[3];
}

// ---------------------------------------------------------------------------
__global__ __launch_bounds__(256)
void vq_loss(float* __restrict__ out) {
    const float* part = out + PART_OFF;
    __shared__ double red[256];
    const int tid = threadIdx.x;
    double s = 0.0;
    for (int i = tid; i < 16384; i += 256) s += (double)part[i];
    red[tid] = s;
    __syncthreads();
    for (int off = 128; off > 0; off >>= 1) {
        if (tid < off) red[tid] += red[tid + off];
        __syncthreads();
    }
    if (tid == 0)
        out[LOSS_OFF] = (float)(1.25 * red[0] / (double)((size_t)N_ROWS * DIM));
}

// ---------------------------------------------------------------------------
__global__ __launch_bounds__(256)
void vq_encodings(float* __restrict__ out) {
    const float* idxf = out + IDX_OFF;
    float4* enc4 = (float4*)(out + ENC_OFF);
    const size_t total4 = (size_t)N_ROWS * KCB / 4;
    const size_t stride = (size_t)gridDim.x * blockDim.x;
    for (size_t g = (size_t)blockIdx.x * blockDim.x + threadIdx.x; g < total4; g += stride) {
        int n  = (int)(g >> 8);
        int c0 = ((int)g & 255) * 4;
        int r  = (int)idxf[n] - c0;
        float4 v;
        v.x = (r == 0) ? 1.f : 0.f;
        v.y = (r == 1) ? 1.f : 0.f;
        v.z = (r == 2) ? 1.f : 0.f;
        v.w = (r == 3) ? 1.f : 0.f;
        enc4[g] = v;
    }
}

// ---------------------------------------------------------------------------
extern "C" void kernel_launch(void* const* d_in, const int* in_sizes, int n_in,
                              void* d_out, int out_size, void* d_ws, size_t ws_size,
                              hipStream_t stream) {
    const float* X = (const float*)d_in[0];   // [16,4096,256] f32
    const float* E = (const float*)d_in[1];   // [256,1024] f32
    float* out = (float*)d_out;

    vq_prep_a   <<<8192, 256, 0, stream>>>(X, out);
    vq_prep_b   <<<1024,  64, 0, stream>>>(E, out);
    vq_gemm     <<<4096, 256, 0, stream>>>(out);
    vq_combine  <<<256,  256, 0, stream>>>(out);
    vq_rescore  <<<256,  256, 0, stream>>>(X, E, out);
    vq_outputs  <<<16384, 256, 0, stream>>>(X, out);
    vq_loss     <<<1,    256, 0, stream>>>(out);
    vq_encodings<<<2048, 256, 0, stream>>>(out);
}

// Round 6
// 644.794 us; speedup vs baseline: 1.6081x; 1.3232x over previous
//
#include <hip/hip_runtime.h>

#define N_ROWS 65536          // 16*4096
#define DIM    256
#define KCB    1024

// d_out layout (floats), in reference return order
#define Q_OFF    0
#define ENC_OFF  (N_ROWS * DIM)                  // 16777216
#define IDX_OFF  (ENC_OFF + N_ROWS * KCB)        // 83886080
#define LOSS_OFF (IDX_OFF + N_ROWS)              // 83951616

// scratch carved out of the encodings region (overwritten by final kernel)
#define ET_OFF   (ENC_OFF + 0)                   // 262144 f32: E^T
#define NRM_OFF  (ENC_OFF + 262144)              // 1024 f32: ||e||^2
#define IDXI_OFF (ENC_OFF + 263168)              // 65536 int: final argmin
#define PART_OFF (ENC_OFF + 328704)              // 16384 f32: loss partials
#define AMB_OFF  (ENC_OFF + 345088)              // int counter + 65536 int list
#define PMIN_OFF (ENC_OFF + 524288)              // 65536*16 float4 partial minima
#define A2_OFF   (ENC_OFF + 4718592)             // bf16 [65536][512] {hi|lo}
#define BST_OFF  (ENC_OFF + 21495808)            // bf16 [1024][512] {ehi|elo}

// ambiguity gap: worst-case |gemm-dist - f32-chain-dist| ~5e-4; 100x margin.
// round-5 lesson: TAU=0.5 flagged ~63% of rows (gap distribution is dense);
// rescore cost scales linearly with TAU.
#define TAU 0.05f

typedef short  bf16x8 __attribute__((ext_vector_type(8)));
typedef float  f32x4  __attribute__((ext_vector_type(4)));
typedef unsigned short u16x8 __attribute__((ext_vector_type(8)));
#define AS1 __attribute__((address_space(1)))
#define AS3 __attribute__((address_space(3)))

__device__ inline unsigned short f2bf(float x) {
    unsigned u = __float_as_uint(x);
    return (unsigned short)((u + 0x7FFFu + ((u >> 16) & 1u)) >> 16);
}
__device__ inline float bf2f(unsigned short b) {
    return __uint_as_float(((unsigned)b) << 16);
}

// ---------------------------------------------------------------------------
// split X (f32) -> A2 [row][512] bf16: [0,256)=hi, [256,512)=lo
__global__ __launch_bounds__(256)
void vq_prep_a(const float* __restrict__ X, float* __restrict__ out) {
    unsigned short* A2 = (unsigned short*)(out + A2_OFF);
    int gid = blockIdx.x * 256 + threadIdx.x;   // 2M threads, 8 floats each
    int row = gid >> 5;
    int d0  = (gid & 31) * 8;
    const float* xp = X + (size_t)row * DIM + d0;
    float4 v0 = *(const float4*)xp;
    float4 v1 = *(const float4*)(xp + 4);
    float xv[8] = {v0.x, v0.y, v0.z, v0.w, v1.x, v1.y, v1.z, v1.w};
    u16x8 h, l;
#pragma unroll
    for (int i = 0; i < 8; ++i) {
        unsigned short hb = f2bf(xv[i]);
        h[i] = hb;
        l[i] = f2bf(xv[i] - bf2f(hb));
    }
    *(u16x8*)(A2 + (size_t)row * 512 + d0) = h;
    *(u16x8*)(A2 + (size_t)row * 512 + 256 + d0) = l;
}

// ---------------------------------------------------------------------------
// E [256][1024] -> ET [1024][256] f32, nrm [1024], B2 [1024][512] bf16 {hi|lo}
// NOTE: the s += e*e chain + butterfly order must stay identical to the
// known-good round-2 prep (rescore replicates its consumers bit-exactly).
__global__ __launch_bounds__(64)
void vq_prep_b(const float* __restrict__ E, float* __restrict__ out) {
    float* ET  = out + ET_OFF;
    float* nrm = out + NRM_OFF;
    unsigned short* B2 = (unsigned short*)(out + BST_OFF);
    const int k = blockIdx.x, t = threadIdx.x;
    float v[4]; float s = 0.f;
    ushort4 hb, lb;
#pragma unroll
    for (int i = 0; i < 4; ++i) {
        float e = E[(size_t)(t * 4 + i) * KCB + k];
        v[i] = e; s += e * e;
        unsigned short h = f2bf(e);
        ((unsigned short*)&hb)[i] = h;
        ((unsigned short*)&lb)[i] = f2bf(e - bf2f(h));
    }
    *(float4*)(ET + (size_t)k * DIM + t * 4) = *(float4*)v;
    *(ushort4*)(B2 + (size_t)k * 512 + t * 4) = hb;
    *(ushort4*)(B2 + (size_t)k * 512 + 256 + t * 4) = lb;
#pragma unroll
    for (int off = 32; off >= 1; off >>= 1) s += __shfl_xor(s, off);
    if (t == 0) nrm[k] = s;
    if (k == 0 && t == 0) ((int*)(out + AMB_OFF))[0] = 0;   // ambiguous counter
}

// ---------------------------------------------------------------------------
// MFMA distance GEMM: sim = x_hi.e_hi + x_hi.e_lo + x_lo.e_hi  (K=768 virtual)
// 128x128 tile, BK=64, 4 waves, 16x16x32 bf16 MFMA, global_load_lds width 16.
// Epilogue: per-row top-2 -> pmin[row][cb*2 + wc]  (16 slots per row).
__global__ __launch_bounds__(256, 3)
void vq_gemm(float* __restrict__ out) {
    __shared__ short lds[16384];   // A tile [128][64] @0, B tile [128][64] @8192
    const unsigned short* A2 = (const unsigned short*)(out + A2_OFF);
    const unsigned short* B2 = (const unsigned short*)(out + BST_OFF);
    const float* nrm = out + NRM_OFF;
    float4* pmin = (float4*)(out + PMIN_OFF);

    const int orig = blockIdx.x;
    const int mapped = (orig & 7) * 512 + (orig >> 3);   // XCD-contiguous
    const int rb = mapped >> 3, cb = mapped & 7;
    const int row0 = rb * 128, col0 = cb * 128;

    const int tid = threadIdx.x;
    const int lane = tid & 63, l15 = lane & 15, lhi = lane >> 4;
    const int w = tid >> 6, wr = w >> 1, wc = w & 1;

    f32x4 acc[4][4];
#pragma unroll
    for (int i = 0; i < 4; ++i)
#pragma unroll
        for (int j = 0; j < 4; ++j) acc[i][j] = (f32x4){0.f, 0.f, 0.f, 0.f};

    const int sr = tid >> 3;          // staging row within 32-row chunk group
    const int sk = (tid & 7) * 8;     // staging k offset (bf16 units)
    const int wofs = (tid & 192) * 16;  // wave-uniform LDS byte base piece

    for (int ks = 0; ks < 12; ++ks) {
        const int phase = ks >> 2, kr = (ks & 3) * 64;
        const int ak = (phase == 2 ? 256 : 0) + kr;   // hi,hi,lo
        const int bk = (phase == 1 ? 256 : 0) + kr;   // ehi,elo,ehi
        __syncthreads();
#pragma unroll
        for (int i = 0; i < 4; ++i) {
            int r = i * 32 + sr;
            __builtin_amdgcn_global_load_lds(
                (const AS1 unsigned*)(A2 + (size_t)(row0 + r) * 512 + ak + sk),
                (AS3 unsigned*)((char*)lds + i * 4096 + wofs), 16, 0, 0);
        }
#pragma unroll
        for (int i = 0; i < 4; ++i) {
            int r = i * 32 + sr;
            __builtin_amdgcn_global_load_lds(
                (const AS1 unsigned*)(B2 + (size_t)(col0 + r) * 512 + bk + sk),
                (AS3 unsigned*)((char*)lds + 16384 + i * 4096 + wofs), 16, 0, 0);
        }
        asm volatile("s_waitcnt vmcnt(0)" ::: "memory");
        __syncthreads();
#pragma unroll
        for (int kk = 0; kk < 2; ++kk) {
            bf16x8 af[4], bfr[4];
#pragma unroll
            for (int mi = 0; mi < 4; ++mi)
                af[mi] = *(const bf16x8*)&lds[(wr * 64 + mi * 16 + l15) * 64 + kk * 32 + lhi * 8];
#pragma unroll
            for (int ni = 0; ni < 4; ++ni)
                bfr[ni] = *(const bf16x8*)&lds[8192 + (wc * 64 + ni * 16 + l15) * 64 + kk * 32 + lhi * 8];
#pragma unroll
            for (int mi = 0; mi < 4; ++mi)
#pragma unroll
                for (int ni = 0; ni < 4; ++ni)
                    acc[mi][ni] = __builtin_amdgcn_mfma_f32_16x16x32_bf16(
                        af[mi], bfr[ni], acc[mi][ni], 0, 0, 0);
        }
    }

    // epilogue: dist = nrm - 2*sim; per-row top-2 over this wave's 64 cols
    float nv[4];
#pragma unroll
    for (int ni = 0; ni < 4; ++ni) nv[ni] = nrm[col0 + wc * 64 + ni * 16 + l15];
#pragma unroll
    for (int mi = 0; mi < 4; ++mi)
#pragma unroll
        for (int j = 0; j < 4; ++j) {
            float a = 3.4e38f, b = 3.4e38f; int ia = 0;
#pragma unroll
            for (int ni = 0; ni < 4; ++ni) {
                float dist = fmaf(-2.f, acc[mi][ni][j], nv[ni]);
                int col = col0 + wc * 64 + ni * 16 + l15;
                if (dist < a) { b = a; a = dist; ia = col; }
                else if (dist < b) b = dist;
            }
#pragma unroll
            for (int off = 1; off < 16; off <<= 1) {
                float oa = __shfl_xor(a, off);
                float ob = __shfl_xor(b, off);
                int   oi = __shfl_xor(ia, off);
                if (oa < a || (oa == a && oi < ia)) { b = fminf(a, ob); a = oa; ia = oi; }
                else b = fminf(b, oa);
            }
            if (l15 == 0) {
                int grow = row0 + wr * 64 + mi * 16 + lhi * 4 + j;
                float4 pv;
                pv.x = a; pv.y = b; pv.z = __int_as_float(ia); pv.w = 0.f;
                pmin[(size_t)grow * 16 + cb * 2 + wc] = pv;   // per-(cb,wc) slot
            }
        }
}

// ---------------------------------------------------------------------------
// merge 16 partials per row; flag ambiguous rows (gap < TAU)
__global__ __launch_bounds__(256)
void vq_combine(float* __restrict__ out) {
    const float4* pmin = (const float4*)(out + PMIN_OFF);
    int* idxi = (int*)(out + IDXI_OFF);
    int* amb  = (int*)(out + AMB_OFF);
    const int row = blockIdx.x * 256 + threadIdx.x;
    float a = 3.4e38f, b = 3.4e38f; int ia = 0;
#pragma unroll
    for (int s = 0; s < 16; ++s) {
        float4 p = pmin[(size_t)row * 16 + s];
        int oi = __float_as_int(p.z);
        if (p.x < a || (p.x == a && oi < ia)) { b = fminf(a, p.y); a = p.x; ia = oi; }
        else b = fminf(b, p.x);
    }
    idxi[row] = ia;
    if (b - a < TAU) {
        int pos = atomicAdd(amb, 1);
        if (pos < 65536) amb[1 + pos] = row;
    }
}

// ---------------------------------------------------------------------------
// rescore of ambiguous rows: BIT-EXACT replica of the known-good round-2 f32
// arithmetic (fmaf chain d=0..255, dist = fmaf(-2, acc, nrm), first-index
// argmin). Must NOT be "more exact" — near-ties must resolve like numpy/f32.
__global__ __launch_bounds__(256)
void vq_rescore(const float* __restrict__ X, const float* __restrict__ E,
                float* __restrict__ out) {
    __shared__ float xs[256];
    __shared__ float rv[256];
    __shared__ int   ri[256];
    const float* nrm = out + NRM_OFF;
    const int* amb = (const int*)(out + AMB_OFF);
    int* idxi = (int*)(out + IDXI_OFF);
    int count = amb[0]; if (count > 65536) count = 65536;
    for (int it = blockIdx.x; it < count; it += gridDim.x) {
        const int row = amb[1 + it];
        __syncthreads();
        xs[threadIdx.x] = X[(size_t)row * DIM + threadIdx.x];
        __syncthreads();
        float best = 3.4e38f; int bi = 0;
        for (int cc = 0; cc < 4; ++cc) {
            const int code = cc * 256 + threadIdx.x;   // ascending per thread
            float acc = 0.f;
            for (int d = 0; d < 256; ++d)
                acc = fmaf(xs[d], E[(size_t)d * KCB + code], acc);
            float dist = fmaf(-2.f, acc, nrm[code]);
            if (dist < best) { best = dist; bi = code; }
        }
        rv[threadIdx.x] = best; ri[threadIdx.x] = bi;
        __syncthreads();
        for (int off = 128; off > 0; off >>= 1) {
            if (threadIdx.x < off) {
                float ov = rv[threadIdx.x + off]; int oi = ri[threadIdx.x + off];
                if (ov < rv[threadIdx.x] || (ov == rv[threadIdx.x] && oi < ri[threadIdx.x])) {
                    rv[threadIdx.x] = ov; ri[threadIdx.x] = oi;
                }
            }
            __syncthreads();
        }
        if (threadIdx.x == 0) idxi[row] = ri[0];
    }
}

// ---------------------------------------------------------------------------
// outputs: quantized_st (gather from E^T), indices-as-float, loss partials
__global__ __launch_bounds__(256)
void vq_outputs(const float* __restrict__ X, float* __restrict__ out) {
    const float* ET  = out + ET_OFF;
    const int*   idx = (const int*)(out + IDXI_OFF);
    float*       part = out + PART_OFF;
    __shared__ float red[4];
    const int row  = blockIdx.x * 4 + (threadIdx.x >> 6);
    const int lane = threadIdx.x & 63;
    const int id   = idx[row];
    float4 e = *(const float4*)(ET + (size_t)id * DIM + lane * 4);
    float4 x = *(const float4*)(X + (size_t)row * DIM + lane * 4);
    float dx = e.x - x.x, dy = e.y - x.y, dz = e.z - x.z, dw = e.w - x.w;
    float4 q;
    q.x = x.x + dx; q.y = x.y + dy; q.z = x.z + dz; q.w = x.w + dw;
    *(float4*)(out + Q_OFF + (size_t)row * DIM + lane * 4) = q;
    float s = dx * dx + dy * dy + dz * dz + dw * dw;
#pragma unroll
    for (int off = 32; off >= 1; off >>= 1) s += __shfl_xor(s, off);
    if (lane == 0) {
        red[threadIdx.x >> 6] = s;
        out[IDX_OFF + row] = (float)id;
    }
    __syncthreads();
    if (threadIdx.x == 0) part[blockIdx.x] = red[0] + red[1] + red[2] + red[3];
}

// ---------------------------------------------------------------------------
__global__ __launch_bounds__(256)
void vq_loss(float* __restrict__ out) {
    const float* part = out + PART_OFF;
    __shared__ double red[256];
    const int tid = threadIdx.x;
    double s = 0.0;
    for (int i = tid; i < 16384; i += 256) s += (double)part[i];
    red[tid] = s;
    __syncthreads();
    for (int off = 128; off > 0; off >>= 1) {
        if (tid < off) red[tid] += red[tid + off];
        __syncthreads();
    }
    if (tid == 0)
        out[LOSS_OFF] = (float)(1.25 * red[0] / (double)((size_t)N_ROWS * DIM));
}

// ---------------------------------------------------------------------------
__global__ __launch_bounds__(256)
void vq_encodings(float* __restrict__ out) {
    const float* idxf = out + IDX_OFF;
    float4* enc4 = (float4*)(out + ENC_OFF);
    const size_t total4 = (size_t)N_ROWS * KCB / 4;
    const size_t stride = (size_t)gridDim.x * blockDim.x;
    for (size_t g = (size_t)blockIdx.x * blockDim.x + threadIdx.x; g < total4; g += stride) {
        int n  = (int)(g >> 8);
        int c0 = ((int)g & 255) * 4;
        int r  = (int)idxf[n] - c0;
        float4 v;
        v.x = (r == 0) ? 1.f : 0.f;
        v.y = (r == 1) ? 1.f : 0.f;
        v.z = (r == 2) ? 1.f : 0.f;
        v.w = (r == 3) ? 1.f : 0.f;
        enc4[g] = v;
    }
}

// ---------------------------------------------------------------------------
extern "C" void kernel_launch(void* const* d_in, const int* in_sizes, int n_in,
                              void* d_out, int out_size, void* d_ws, size_t ws_size,
                              hipStream_t stream) {
    const float* X = (const float*)d_in[0];   // [16,4096,256] f32
    const float* E = (const float*)d_in[1];   // [256,1024] f32
    float* out = (float*)d_out;

    vq_prep_a   <<<8192, 256, 0, stream>>>(X, out);
    vq_prep_b   <<<1024,  64, 0, stream>>>(E, out);
    vq_gemm     <<<4096, 256, 0, stream>>>(out);
    vq_combine  <<<256,  256, 0, stream>>>(out);
    vq_rescore  <<<2048, 256, 0, stream>>>(X, E, out);
    vq_outputs  <<<16384, 256, 0, stream>>>(X, out);
    vq_loss     <<<1,    256, 0, stream>>>(out);
    vq_encodings<<<2048, 256, 0, stream>>>(out);
}